// Round 13
// baseline (515.054 us; speedup 1.0000x reference)
//
#include <hip/hip_runtime.h>
#include <hip/hip_bf16.h>

#define Sq 2048
#define Dm 2048
#define HDim 3072
#define QKVDim 9216
#define NH 24
#define DH 128
#define FF 8192
#define ATT_SCALE 0.08838834764831845f

using bf16 = __hip_bfloat16;
typedef __attribute__((ext_vector_type(8))) short bf16x8;
typedef __attribute__((ext_vector_type(4))) float f32x4;
typedef unsigned int u32;
typedef unsigned long long u64;
typedef __attribute__((ext_vector_type(4))) u32 u32x4;

__device__ __forceinline__ void gload_lds16(const void* g, void* l) {
    __builtin_amdgcn_global_load_lds(
        (const __attribute__((address_space(1))) void*)g,
        (__attribute__((address_space(3))) void*)l, 16, 0, 0);
}

#define BARRIER() do { asm volatile("" ::: "memory"); \
    __builtin_amdgcn_s_barrier(); \
    asm volatile("" ::: "memory"); } while (0)

// ---------------- LayerNorm + RMSNorm fused ----------------
__global__ __launch_bounds__(256) void ln_rms_kernel(
    const float* __restrict__ x, const float* __restrict__ g, const float* __restrict__ b,
    const float* __restrict__ ag, float* __restrict__ xnf, bf16* __restrict__ h)
{
    __shared__ float redA[4], redB[4], redC[4];
    int row = blockIdx.x;
    int t = threadIdx.x;
    int lane = t & 63, wid = t >> 6;
    const float* xr = x + (size_t)row * Dm;

    float v[8];
    float sum = 0.f, ssq = 0.f;
#pragma unroll
    for (int i = 0; i < 8; i++) {
        float f = xr[t + 256 * i];
        v[i] = f; sum += f; ssq += f * f;
    }
#pragma unroll
    for (int off = 32; off > 0; off >>= 1) {
        sum += __shfl_down(sum, off);
        ssq += __shfl_down(ssq, off);
    }
    if (lane == 0) { redA[wid] = sum; redB[wid] = ssq; }
    __syncthreads();
    sum = redA[0] + redA[1] + redA[2] + redA[3];
    ssq = redB[0] + redB[1] + redB[2] + redB[3];
    float mu = sum * (1.f / Dm);
    float var = ssq * (1.f / Dm) - mu * mu;
    float rstd = rsqrtf(var + 1e-5f);

    float xn[8];
    float s2 = 0.f;
#pragma unroll
    for (int i = 0; i < 8; i++) {
        int col = t + 256 * i;
        float xv = (v[i] - mu) * rstd * g[col] + b[col];
        xn[i] = xv;
        xnf[(size_t)row * Dm + col] = xv;
        s2 += xv * xv;
    }
#pragma unroll
    for (int off = 32; off > 0; off >>= 1) s2 += __shfl_down(s2, off);
    if (lane == 0) redC[wid] = s2;
    __syncthreads();
    s2 = redC[0] + redC[1] + redC[2] + redC[3];
    float rms = rsqrtf(s2 * (1.f / Dm) + 1e-5f);
#pragma unroll
    for (int i = 0; i < 8; i++) {
        int col = t + 256 * i;
        h[(size_t)row * Dm + col] = __float2bfloat16(xn[i] * rms * ag[col]);
    }
}

// ---------------- transpose + fp32->bf16 convert: W[K][N] -> Wt[N][K] ----------------
__global__ __launch_bounds__(256) void transpose_cvt_kernel(
    const float* __restrict__ W, bf16* __restrict__ Wt, int K, int N)
{
    __shared__ float tile[32][36];
    int n0 = blockIdx.x * 32, k0 = blockIdx.y * 32;
    int t = threadIdx.x;
    int r = t >> 3, c4 = (t & 7) * 4;
    f32x4 v = *reinterpret_cast<const f32x4*>(W + (size_t)(k0 + r) * N + n0 + c4);
    *reinterpret_cast<f32x4*>(&tile[r][c4]) = v;
    __syncthreads();
    int nr = t >> 3, kc = (t & 7) * 4;
    bf16 o4[4];
    o4[0] = __float2bfloat16(tile[kc + 0][nr]);
    o4[1] = __float2bfloat16(tile[kc + 1][nr]);
    o4[2] = __float2bfloat16(tile[kc + 2][nr]);
    o4[3] = __float2bfloat16(tile[kc + 3][nr]);
    *reinterpret_cast<u64*>(Wt + (size_t)(n0 + nr) * K + k0 + kc) = *reinterpret_cast<const u64*>(o4);
}

// 3-matrix variant for fused QKV weight transpose (z selects matrix)
__global__ __launch_bounds__(256) void transpose_cvt3_kernel(
    const float* __restrict__ Wa, const float* __restrict__ Wb, const float* __restrict__ Wc,
    bf16* __restrict__ Wt, int K, int N)
{
    __shared__ float tile[32][36];
    const float* W = blockIdx.z == 0 ? Wa : (blockIdx.z == 1 ? Wb : Wc);
    bf16* dst = Wt + (size_t)blockIdx.z * N * K;
    int n0 = blockIdx.x * 32, k0 = blockIdx.y * 32;
    int t = threadIdx.x;
    int r = t >> 3, c4 = (t & 7) * 4;
    f32x4 v = *reinterpret_cast<const f32x4*>(W + (size_t)(k0 + r) * N + n0 + c4);
    *reinterpret_cast<f32x4*>(&tile[r][c4]) = v;
    __syncthreads();
    int nr = t >> 3, kc = (t & 7) * 4;
    bf16 o4[4];
    o4[0] = __float2bfloat16(tile[kc + 0][nr]);
    o4[1] = __float2bfloat16(tile[kc + 1][nr]);
    o4[2] = __float2bfloat16(tile[kc + 2][nr]);
    o4[3] = __float2bfloat16(tile[kc + 3][nr]);
    *reinterpret_cast<u64*>(dst + (size_t)(n0 + nr) * K + k0 + kc) = *reinterpret_cast<const u64*>(o4);
}

// ---------------- fused: hb = bf16(xnf); out = xnf + b2 ----------------
__global__ __launch_bounds__(256) void cvt_prefill_kernel(
    const float* __restrict__ xnf, const float* __restrict__ bias,
    bf16* __restrict__ hb, float* __restrict__ o, int N)
{
    int i = (blockIdx.x * 256 + threadIdx.x) * 8;
    int col = i % N;
    f32x4 a = *reinterpret_cast<const f32x4*>(xnf + i);
    f32x4 b = *reinterpret_cast<const f32x4*>(xnf + i + 4);
    bf16 r[8];
#pragma unroll
    for (int j = 0; j < 4; j++) { r[j] = __float2bfloat16(a[j]); r[4 + j] = __float2bfloat16(b[j]); }
    *reinterpret_cast<u32x4*>(hb + i) = *reinterpret_cast<const u32x4*>(r);
    f32x4 b0 = *reinterpret_cast<const f32x4*>(bias + col);
    f32x4 b1v = *reinterpret_cast<const f32x4*>(bias + col + 4);
    f32x4 o0 = {a[0] + b0[0], a[1] + b0[1], a[2] + b0[2], a[3] + b0[3]};
    f32x4 o1 = {b[0] + b1v[0], b[1] + b1v[1], b[2] + b1v[2], b[3] + b1v[3]};
    *reinterpret_cast<f32x4*>(o + i) = o0;
    *reinterpret_cast<f32x4*>(o + i + 4) = o1;
}

// ---------------- 128x128 bf16 MFMA GEMM (m97 structure, BK=64, swizzled) ------
// Used for the QKV projection (grid 72x16 doesn't fit 256^2 cleanly).
template <int EPI>
__global__ __launch_bounds__(256, 4) void gemm_kernel(
    const bf16* __restrict__ A, const bf16* __restrict__ Bt,
    int M, int N, int K, int Ksplit,
    bf16* Cb, float* Cf, const float* __restrict__ bias)
{
    __shared__ __align__(16) bf16 As[128 * 64];
    __shared__ __align__(16) bf16 Bs[128 * 64];
    int m0 = blockIdx.y * 128, n0 = blockIdx.x * 128;
    int kbeg = blockIdx.z * Ksplit, kend = kbeg + Ksplit;
    int tid = threadIdx.x;
    int lane = tid & 63, w = tid >> 6;
    int wr = w >> 1, wc = w & 1;
    int l15 = lane & 15, lhi = lane >> 4;

    int srow = lane >> 3;
    int scol = ((lane & 7) ^ (lane >> 3)) * 8;

    const f32x4 zero4 = {0.f, 0.f, 0.f, 0.f};
    f32x4 acc[4][4];
#pragma unroll
    for (int m = 0; m < 4; m++)
#pragma unroll
        for (int n = 0; n < 4; n++) acc[m][n] = zero4;

    for (int k0 = kbeg; k0 < kend; k0 += 64) {
        __syncthreads();
#pragma unroll
        for (int c = 0; c < 4; c++) {
            int row = w * 32 + c * 8 + srow;
            gload_lds16(A + (size_t)(m0 + row) * K + k0 + scol,
                        (char*)As + w * 4096 + c * 1024);
            gload_lds16(Bt + (size_t)(n0 + row) * K + k0 + scol,
                        (char*)Bs + w * 4096 + c * 1024);
        }
        __syncthreads();
#pragma unroll
        for (int ks = 0; ks < 2; ks++) {
            bf16x8 af[4], bfr[4];
#pragma unroll
            for (int m = 0; m < 4; m++) {
                int r = wr * 64 + m * 16 + l15;
                af[m] = *reinterpret_cast<const bf16x8*>(
                    &As[r * 64 + (((ks << 2) + lhi) ^ (r & 7)) * 8]);
            }
#pragma unroll
            for (int n = 0; n < 4; n++) {
                int r = wc * 64 + n * 16 + l15;
                bfr[n] = *reinterpret_cast<const bf16x8*>(
                    &Bs[r * 64 + (((ks << 2) + lhi) ^ (r & 7)) * 8]);
            }
#pragma unroll
            for (int m = 0; m < 4; m++)
#pragma unroll
                for (int n = 0; n < 4; n++)
                    acc[m][n] = __builtin_amdgcn_mfma_f32_16x16x32_bf16(af[m], bfr[n], acc[m][n], 0, 0, 0);
        }
    }

#pragma unroll
    for (int m = 0; m < 4; m++) {
        int row = m0 + wr * 64 + m * 16 + lhi * 4;
#pragma unroll
        for (int n = 0; n < 4; n++) {
            int col = n0 + wc * 64 + n * 16 + l15;
#pragma unroll
            for (int j = 0; j < 4; j++) {
                float vv = acc[m][n][j];
                size_t idx = (size_t)(row + j) * N + col;
                if (EPI == 0) {
                    Cb[idx] = __float2bfloat16(vv);
                } else if (EPI == 2) {
                    float o = vv + bias[col];
                    float u = 1.5957691216057308f * (o + 0.044715f * o * o * o);
                    Cb[idx] = __float2bfloat16(o / (1.0f + __expf(-u)));
                } else {
                    atomicAdd(&Cf[idx], vv);
                }
            }
        }
    }
}

// ---------------- 256x256 bf16 MFMA GEMM, 4-phase counted-vmcnt (8-phase/2-tile) --
// 512 threads = 8 waves (2M x 4N); per-wave C = 128x64 (8 m-frags x 4 n-frags).
// LDS: As/Bs[2 buf][2 half][128 rows][64 K], 128 KiB total, XOR swizzle slot^(r&7).
// Wave (wr,wc) touches ONLY A-half wr and B-half wc>>1.
// Phase reads (iter t, buf b=t&1):  P0: A m0-3 + B n0,n1 (12 b128) | P1: A m4-7 (8)
//   | P2: B n2,n3 (4) | P3: none.  => A-half reads of b done after P1; B after P2.
// Phase stages (2 gload_lds each): P0: B0(t+1)->b^1 | P1: B1(t+1)->b^1
//   | P2: A0(t+2)->b | P3: A1(t+2)->b.  Every write targets a region whose reads
//   completed a phase earlier (ledger-verified).  Gate: vmcnt(4) at P3 retires
//   through B1(t+1) (tile t+1 resident), leaves A(t+2)'s 4 loads in flight.
// Prologue: A0(0) A1(0) B0(0) B1(0) A0(1) A1(1); vmcnt(4); barrier.
// Out-of-range stages clamp the SOURCE (vmcnt arithmetic exact); junk lands only
// in dead regions. T5 setprio around each 16-MFMA cluster.
template <int EPI>
__global__ __launch_bounds__(512, 2) void gemm256_kernel(
    const bf16* __restrict__ A, const bf16* __restrict__ Bt,
    int M, int N, int K, int Ksplit,
    bf16* Cb, float* Cf, const float* __restrict__ bias)
{
    __shared__ __align__(16) bf16 As[2][2][128 * 64];
    __shared__ __align__(16) bf16 Bs[2][2][128 * 64];
    int m0 = blockIdx.y * 256, n0 = blockIdx.x * 256;
    int kbeg = blockIdx.z * Ksplit;
    int nt = Ksplit >> 6;
    int tid = threadIdx.x;
    int lane = tid & 63, w = tid >> 6;
    int wr = w >> 2, wc = w & 3;
    int l15 = lane & 15, lhi = lane >> 4;
    int hb = wc >> 1;
    int x7 = l15 & 7;                 // row&7 for all frag rows

    int lrow = lane >> 3;             // staging row-in-group 0..7
    int scol = ((lane & 7) ^ lrow) * 8;

    f32x4 acc[8][4];
    const f32x4 zero4 = {0.f, 0.f, 0.f, 0.f};
#pragma unroll
    for (int mm = 0; mm < 8; mm++)
#pragma unroll
        for (int nn = 0; nn < 4; nn++) acc[mm][nn] = zero4;

    auto stage = [&](int op, int h, int tau) {   // op 0=A, 1=B
        int ts = tau < nt ? tau : 0;             // clamp source, count stays exact
        const bf16* base = op ? Bt : A;
        int r0 = (op ? n0 : m0) + h * 128 + w * 8 + lrow;
        const bf16* src = base + (size_t)r0 * K + kbeg + ts * 64 + scol;
        char* dst = (char*)(op ? &Bs[tau & 1][h][0] : &As[tau & 1][h][0]) + w * 1024;
        gload_lds16(src, dst);
        gload_lds16(src + (size_t)64 * K, dst + 8192);
    };

    // prologue
    stage(0, 0, 0); stage(0, 1, 0); stage(1, 0, 0); stage(1, 1, 0);
    stage(0, 0, 1); stage(0, 1, 1);
    asm volatile("s_waitcnt vmcnt(4)" ::: "memory");
    BARRIER();

    for (int t = 0; t < nt; ++t) {
        int buf = t & 1;
        bf16x8 a0[4][2], a1[4][2], bA[2][2], bB[2][2];

        // ---- P0: read A m0-3 + B n0,n1; stage B0(t+1); MFMA (m0-3 x n0,n1) ----
#pragma unroll
        for (int m = 0; m < 4; m++) {
            int r = m * 16 + l15;
            a0[m][0] = *reinterpret_cast<const bf16x8*>(&As[buf][wr][r * 64 + ((lhi ^ x7) << 3)]);
            a0[m][1] = *reinterpret_cast<const bf16x8*>(&As[buf][wr][r * 64 + (((4 + lhi) ^ x7) << 3)]);
        }
#pragma unroll
        for (int n = 0; n < 2; n++) {
            int rb = (wc & 1) * 64 + n * 16 + l15;
            bA[n][0] = *reinterpret_cast<const bf16x8*>(&Bs[buf][hb][rb * 64 + ((lhi ^ x7) << 3)]);
            bA[n][1] = *reinterpret_cast<const bf16x8*>(&Bs[buf][hb][rb * 64 + (((4 + lhi) ^ x7) << 3)]);
        }
        stage(1, 0, t + 1);
        BARRIER();
        __builtin_amdgcn_s_setprio(1);
#pragma unroll
        for (int m = 0; m < 4; m++)
#pragma unroll
            for (int n = 0; n < 2; n++) {
                acc[m][n] = __builtin_amdgcn_mfma_f32_16x16x32_bf16(a0[m][0], bA[n][0], acc[m][n], 0, 0, 0);
                acc[m][n] = __builtin_amdgcn_mfma_f32_16x16x32_bf16(a0[m][1], bA[n][1], acc[m][n], 0, 0, 0);
            }
        __builtin_amdgcn_s_setprio(0);
        BARRIER();

        // ---- P1: read A m4-7; stage B1(t+1); MFMA (m4-7 x n0,n1) ----
#pragma unroll
        for (int m = 0; m < 4; m++) {
            int r = 64 + m * 16 + l15;
            a1[m][0] = *reinterpret_cast<const bf16x8*>(&As[buf][wr][r * 64 + ((lhi ^ x7) << 3)]);
            a1[m][1] = *reinterpret_cast<const bf16x8*>(&As[buf][wr][r * 64 + (((4 + lhi) ^ x7) << 3)]);
        }
        stage(1, 1, t + 1);
        BARRIER();
        __builtin_amdgcn_s_setprio(1);
#pragma unroll
        for (int m = 0; m < 4; m++)
#pragma unroll
            for (int n = 0; n < 2; n++) {
                acc[4 + m][n] = __builtin_amdgcn_mfma_f32_16x16x32_bf16(a1[m][0], bA[n][0], acc[4 + m][n], 0, 0, 0);
                acc[4 + m][n] = __builtin_amdgcn_mfma_f32_16x16x32_bf16(a1[m][1], bA[n][1], acc[4 + m][n], 0, 0, 0);
            }
        __builtin_amdgcn_s_setprio(0);
        BARRIER();

        // ---- P2: read B n2,n3; stage A0(t+2); MFMA (m0-3 x n2,n3) ----
#pragma unroll
        for (int n = 0; n < 2; n++) {
            int rb = (wc & 1) * 64 + (2 + n) * 16 + l15;
            bB[n][0] = *reinterpret_cast<const bf16x8*>(&Bs[buf][hb][rb * 64 + ((lhi ^ x7) << 3)]);
            bB[n][1] = *reinterpret_cast<const bf16x8*>(&Bs[buf][hb][rb * 64 + (((4 + lhi) ^ x7) << 3)]);
        }
        stage(0, 0, t + 2);
        BARRIER();
        __builtin_amdgcn_s_setprio(1);
#pragma unroll
        for (int m = 0; m < 4; m++)
#pragma unroll
            for (int n = 0; n < 2; n++) {
                acc[m][2 + n] = __builtin_amdgcn_mfma_f32_16x16x32_bf16(a0[m][0], bB[n][0], acc[m][2 + n], 0, 0, 0);
                acc[m][2 + n] = __builtin_amdgcn_mfma_f32_16x16x32_bf16(a0[m][1], bB[n][1], acc[m][2 + n], 0, 0, 0);
            }
        __builtin_amdgcn_s_setprio(0);
        BARRIER();

        // ---- P3: stage A1(t+2); GATE vmcnt(4); MFMA (m4-7 x n2,n3) ----
        stage(0, 1, t + 2);
        asm volatile("s_waitcnt vmcnt(4)" ::: "memory");
        BARRIER();
        __builtin_amdgcn_s_setprio(1);
#pragma unroll
        for (int m = 0; m < 4; m++)
#pragma unroll
            for (int n = 0; n < 2; n++) {
                acc[4 + m][2 + n] = __builtin_amdgcn_mfma_f32_16x16x32_bf16(a1[m][0], bB[n][0], acc[4 + m][2 + n], 0, 0, 0);
                acc[4 + m][2 + n] = __builtin_amdgcn_mfma_f32_16x16x32_bf16(a1[m][1], bB[n][1], acc[4 + m][2 + n], 0, 0, 0);
            }
        __builtin_amdgcn_s_setprio(0);
        BARRIER();
    }
    asm volatile("s_waitcnt vmcnt(0)" ::: "memory");

#pragma unroll
    for (int mm = 0; mm < 8; mm++) {
        int row = m0 + wr * 128 + mm * 16 + lhi * 4;
#pragma unroll
        for (int nn = 0; nn < 4; nn++) {
            int col = n0 + wc * 64 + nn * 16 + l15;
#pragma unroll
            for (int j = 0; j < 4; j++) {
                float vv = acc[mm][nn][j];
                size_t idx = (size_t)(row + j) * N + col;
                if (EPI == 0) {
                    Cb[idx] = __float2bfloat16(vv);
                } else if (EPI == 2) {
                    float o = vv + bias[col];
                    float u = 1.5957691216057308f * (o + 0.044715f * o * o * o);
                    Cb[idx] = __float2bfloat16(o / (1.0f + __expf(-u)));
                } else {
                    atomicAdd(&Cf[idx], vv);
                }
            }
        }
    }
}

// ---------------- flash-style causal attention (r12 version, unchanged) --------
__global__ __launch_bounds__(256) void attn_kernel(
    const bf16* __restrict__ qkv, bf16* __restrict__ o)
{
    __shared__ __align__(16) bf16 KsF[2][64 * 128];
    __shared__ __align__(16) bf16 VtF[2][128 * 72];
    __shared__ __align__(16) bf16 Pl[4][16][76];
    int rank = blockIdx.x;
    int qb = (Sq / 64 - 1) - rank / NH;
    int head = rank % NH;
    const bf16* q = qkv + head * DH;
    const bf16* k = qkv + HDim + head * DH;
    const bf16* v = qkv + 2 * HDim + head * DH;
    int tid = threadIdx.x, lane = tid & 63, w = tid >> 6;
    int l15 = lane & 15, lhi = lane >> 4;
    int qrow0 = qb * 64 + w * 16;

    bf16x8 aq[4];
    const bf16* qbase = q + (size_t)(qrow0 + l15) * QKVDim;
#pragma unroll
    for (int kk = 0; kk < 4; kk++)
        aq[kk] = *reinterpret_cast<const bf16x8*>(qbase + kk * 32 + lhi * 8);

    bf16x8 vones;
#pragma unroll
    for (int j = 0; j < 8; j++) vones[j] = (short)0x3F80;

    int krow_st = w * 16;
    int vkv = lhi * 2 + (w & 1) + (w >> 1) * 8;
    int vd0 = l15 * 8;
    int vxr = l15 & 7;
    const bf16* vbase = v + (size_t)vkv * QKVDim + vd0;

    const f32x4 zero4 = {0.f, 0.f, 0.f, 0.f};
    f32x4 acc_o[8];
#pragma unroll
    for (int db = 0; db < 8; db++) acc_o[db] = zero4;
    f32x4 acc_l = zero4;
    float mrow[4];
#pragma unroll
    for (int r = 0; r < 4; r++) mrow[r] = -1e30f;

    {
#pragma unroll
        for (int c = 0; c < 4; c++) {
            int row = krow_st + c * 4 + lhi;
            int cb = l15 ^ (row & 7);
            gload_lds16(k + (size_t)row * QKVDim + cb * 8,
                        (char*)&KsF[0][0] + w * 4096 + c * 1024);
        }
#pragma unroll
        for (int i = 0; i < 4; i++) {
            int kv = vkv + i * 16;
            bf16x8 vv = *reinterpret_cast<const bf16x8*>(vbase + (size_t)(i * 16) * QKVDim);
            int vb = kv >> 3, kr = kv & 7;
#pragma unroll
            for (int j = 0; j < 8; j++)
                VtF[0][(vd0 + j) * 72 + ((vb ^ vxr) << 3) + kr] = ((const bf16*)&vv)[j];
        }
        __syncthreads();
    }

    for (int kb = 0; kb <= qb; kb++) {
        int kv0 = kb * 64;
        int p = kb & 1;
        bf16x8 vreg[4];
        bool pref = (kb < qb);
        if (pref) {
            int nv0 = kv0 + 64;
#pragma unroll
            for (int c = 0; c < 4; c++) {
                int row = krow_st + c * 4 + lhi;
                int cb = l15 ^ (row & 7);
                gload_lds16(k + (size_t)(nv0 + row) * QKVDim + cb * 8,
                            (char*)&KsF[p ^ 1][0] + w * 4096 + c * 1024);
            }
#pragma unroll
            for (int i = 0; i < 4; i++)
                vreg[i] = *reinterpret_cast<const bf16x8*>(
                    vbase + (size_t)(nv0 + i * 16) * QKVDim);
        }

        f32x4 sacc[4];
#pragma unroll
        for (int nb = 0; nb < 4; nb++) {
            sacc[nb] = zero4;
            int krow = nb * 16 + l15;
#pragma unroll
            for (int kk = 0; kk < 4; kk++) {
                const char* kp = (const char*)&KsF[p][0] + krow * 256 +
                                 ((kk * 64 + lhi * 16) ^ ((krow & 7) << 4));
                bf16x8 bk = *reinterpret_cast<const bf16x8*>(kp);
                sacc[nb] = __builtin_amdgcn_mfma_f32_16x16x32_bf16(aq[kk], bk, sacc[nb], 0, 0, 0);
            }
        }

        bool diag = (kb == qb);
        float sv[4][4];
        float pm[4];
#pragma unroll
        for (int r = 0; r < 4; r++) pm[r] = -1e30f;
#pragma unroll
        for (int nb = 0; nb < 4; nb++) {
            int kvc = kv0 + nb * 16 + l15;
#pragma unroll
            for (int r = 0; r < 4; r++) {
                int qr = qrow0 + lhi * 4 + r;
                float s = sacc[nb][r] * ATT_SCALE;
                if (diag && kvc > qr) s = -1e30f;
                sv[nb][r] = s;
                pm[r] = fmaxf(pm[r], s);
            }
        }
#pragma unroll
        for (int off = 1; off < 16; off <<= 1)
#pragma unroll
            for (int r = 0; r < 4; r++)
                pm[r] = fmaxf(pm[r], __shfl_xor(pm[r], off));

        float nm[4];
        bool need = false;
#pragma unroll
        for (int r = 0; r < 4; r++) {
            nm[r] = fmaxf(mrow[r], pm[r]);
            need = need || (pm[r] > mrow[r] + 8.f);
        }
        if (__any(need)) {
#pragma unroll
            for (int r = 0; r < 4; r++) {
                float sc = __expf(mrow[r] - nm[r]);
                mrow[r] = nm[r];
                acc_l[r] *= sc;
#pragma unroll
                for (int db = 0; db < 8; db++) acc_o[db][r] *= sc;
            }
        }

#pragma unroll
        for (int nb = 0; nb < 4; nb++)
#pragma unroll
            for (int r = 0; r < 4; r++)
                sv[nb][r] = __expf(sv[nb][r] - mrow[r]);

#pragma unroll
        for (int nb = 0; nb < 4; nb++)
#pragma unroll
            for (int r = 0; r < 4; r++)
                Pl[w][lhi * 4 + r][nb * 16 + l15] = __float2bfloat16(sv[nb][r]);

#pragma unroll
        for (int ks = 0; ks < 2; ks++) {
            bf16x8 ap = *reinterpret_cast<const bf16x8*>(&Pl[w][l15][ks * 32 + lhi * 8]);
            acc_l = __builtin_amdgcn_mfma_f32_16x16x32_bf16(ap, vones, acc_l, 0, 0, 0);
#pragma unroll
            for (int db = 0; db < 8; db++) {
                int dv = db * 16 + l15;
                int blk = (ks * 4 + lhi) ^ ((dv >> 3) & 7);
                bf16x8 bv = *reinterpret_cast<const bf16x8*>(&VtF[p][dv * 72 + blk * 8]);
                acc_o[db] = __builtin_amdgcn_mfma_f32_16x16x32_bf16(ap, bv, acc_o[db], 0, 0, 0);
            }
        }

        if (pref) {
#pragma unroll
            for (int i = 0; i < 4; i++) {
                int kv = vkv + i * 16;
                int vb = kv >> 3, kr = kv & 7;
#pragma unroll
                for (int j = 0; j < 8; j++)
                    VtF[p ^ 1][(vd0 + j) * 72 + ((vb ^ vxr) << 3) + kr] = ((const bf16*)&vreg[i])[j];
            }
        }
        __syncthreads();
    }

#pragma unroll
    for (int db = 0; db < 8; db++)
#pragma unroll
        for (int r = 0; r < 4; r++) {
            int qr = qrow0 + lhi * 4 + r;
            float val = acc_o[db][r] / acc_l[r];
            o[(size_t)qr * HDim + head * DH + db * 16 + l15] = __float2bfloat16(val);
        }
}

// ---------------- host launch ----------------
extern "C" void kernel_launch(void* const* d_in, const int* in_sizes, int n_in,
                              void* d_out, int out_size, void* d_ws, size_t ws_size,
                              hipStream_t stream)
{
    const float* x     = (const float*)d_in[0];
    const float* ln_g  = (const float*)d_in[1];
    const float* ln_b  = (const float*)d_in[2];
    const float* attng = (const float*)d_in[3];
    const float* Wq    = (const float*)d_in[4];
    const float* Wk    = (const float*)d_in[5];
    const float* Wv    = (const float*)d_in[6];
    const float* Wo    = (const float*)d_in[7];
    const float* W1    = (const float*)d_in[8];
    const float* b1    = (const float*)d_in[9];
    const float* W2    = (const float*)d_in[10];
    const float* b2    = (const float*)d_in[11];
    float* out = (float*)d_out;
    char* ws = (char*)d_ws;

    bf16*  wbuf = (bf16*)(ws + 0);           // 38 MB: transposed weights
    float* xnf  = (float*)(ws + 39845888);   // 16 MB: LN out fp32 -> x2 after Wo accum
    bf16*  hbuf = (bf16*)(ws + 56623104);    //  8 MB: rmsnorm bf16 -> x2 bf16
    bf16*  qkv  = (bf16*)(ws + 65011712);    // 36 MB: fused q|k|v; later FFN hidden
    bf16*  ob_  = (bf16*)(ws + 102760448);   // 12 MB: attention out
    bf16*  gb_  = qkv;

    ln_rms_kernel<<<Sq, 256, 0, stream>>>(x, ln_g, ln_b, attng, xnf, hbuf);

    transpose_cvt3_kernel<<<dim3(HDim / 32, Dm / 32, 3), 256, 0, stream>>>(
        Wq, Wk, Wv, wbuf, Dm, HDim);
    gemm_kernel<0><<<dim3(QKVDim / 128, Sq / 128, 1), 256, 0, stream>>>(
        hbuf, wbuf, Sq, QKVDim, Dm, Dm, qkv, nullptr, nullptr);

    attn_kernel<<<dim3(NH * Sq / 64), 256, 0, stream>>>(qkv, ob_);

    // out-proj: 256^2 8-phase, split-K=4 -> grid 8x8x4 = 256 blocks
    transpose_cvt_kernel<<<dim3(Dm / 32, HDim / 32), 256, 0, stream>>>(Wo, wbuf, HDim, Dm);
    gemm256_kernel<4><<<dim3(Dm / 256, Sq / 256, 4), 512, 0, stream>>>(
        ob_, wbuf, Sq, Dm, HDim, HDim / 4, nullptr, xnf, nullptr);
    cvt_prefill_kernel<<<(Sq * Dm) / (256 * 8), 256, 0, stream>>>(xnf, b2, hbuf, out, Dm);

    // FFN1: 256^2 8-phase, grid 32x8 = 256 blocks
    transpose_cvt_kernel<<<dim3(FF / 32, Dm / 32), 256, 0, stream>>>(W1, wbuf, Dm, FF);
    gemm256_kernel<2><<<dim3(FF / 256, Sq / 256, 1), 512, 0, stream>>>(
        hbuf, wbuf, Sq, FF, Dm, Dm, gb_, nullptr, b1);

    // FFN2: 256^2 8-phase, split-K=4 -> 256 blocks
    transpose_cvt_kernel<<<dim3(Dm / 32, FF / 32), 256, 0, stream>>>(W2, wbuf, FF, Dm);
    gemm256_kernel<4><<<dim3(Dm / 256, Sq / 256, 4), 512, 0, stream>>>(
        gb_, wbuf, Sq, Dm, FF, FF / 4, nullptr, out, nullptr);
}

// Round 14
// 454.884 us; speedup vs baseline: 1.1323x; 1.1323x over previous
//
#include <hip/hip_runtime.h>
#include <hip/hip_bf16.h>

#define Sq 2048
#define Dm 2048
#define HDim 3072
#define QKVDim 9216
#define NH 24
#define DH 128
#define FF 8192
#define ATT_SCALE 0.08838834764831845f

using bf16 = __hip_bfloat16;
typedef __attribute__((ext_vector_type(8))) short bf16x8;
typedef __attribute__((ext_vector_type(4))) float f32x4;
typedef unsigned int u32;
typedef unsigned long long u64;
typedef __attribute__((ext_vector_type(4))) u32 u32x4;

__device__ __forceinline__ void gload_lds16(const void* g, void* l) {
    __builtin_amdgcn_global_load_lds(
        (const __attribute__((address_space(1))) void*)g,
        (__attribute__((address_space(3))) void*)l, 16, 0, 0);
}

// ---------------- LayerNorm + RMSNorm fused ----------------
__global__ __launch_bounds__(256) void ln_rms_kernel(
    const float* __restrict__ x, const float* __restrict__ g, const float* __restrict__ b,
    const float* __restrict__ ag, float* __restrict__ xnf, bf16* __restrict__ h)
{
    __shared__ float redA[4], redB[4], redC[4];
    int row = blockIdx.x;
    int t = threadIdx.x;
    int lane = t & 63, wid = t >> 6;
    const float* xr = x + (size_t)row * Dm;

    float v[8];
    float sum = 0.f, ssq = 0.f;
#pragma unroll
    for (int i = 0; i < 8; i++) {
        float f = xr[t + 256 * i];
        v[i] = f; sum += f; ssq += f * f;
    }
#pragma unroll
    for (int off = 32; off > 0; off >>= 1) {
        sum += __shfl_down(sum, off);
        ssq += __shfl_down(ssq, off);
    }
    if (lane == 0) { redA[wid] = sum; redB[wid] = ssq; }
    __syncthreads();
    sum = redA[0] + redA[1] + redA[2] + redA[3];
    ssq = redB[0] + redB[1] + redB[2] + redB[3];
    float mu = sum * (1.f / Dm);
    float var = ssq * (1.f / Dm) - mu * mu;
    float rstd = rsqrtf(var + 1e-5f);

    float xn[8];
    float s2 = 0.f;
#pragma unroll
    for (int i = 0; i < 8; i++) {
        int col = t + 256 * i;
        float xv = (v[i] - mu) * rstd * g[col] + b[col];
        xn[i] = xv;
        xnf[(size_t)row * Dm + col] = xv;
        s2 += xv * xv;
    }
#pragma unroll
    for (int off = 32; off > 0; off >>= 1) s2 += __shfl_down(s2, off);
    if (lane == 0) redC[wid] = s2;
    __syncthreads();
    s2 = redC[0] + redC[1] + redC[2] + redC[3];
    float rms = rsqrtf(s2 * (1.f / Dm) + 1e-5f);
#pragma unroll
    for (int i = 0; i < 8; i++) {
        int col = t + 256 * i;
        h[(size_t)row * Dm + col] = __float2bfloat16(xn[i] * rms * ag[col]);
    }
}

// ---------------- transpose + fp32->bf16 convert: W[K][N] -> Wt[N][K] ----------------
__global__ __launch_bounds__(256) void transpose_cvt_kernel(
    const float* __restrict__ W, bf16* __restrict__ Wt, int K, int N)
{
    __shared__ float tile[32][36];
    int n0 = blockIdx.x * 32, k0 = blockIdx.y * 32;
    int t = threadIdx.x;
    int r = t >> 3, c4 = (t & 7) * 4;
    f32x4 v = *reinterpret_cast<const f32x4*>(W + (size_t)(k0 + r) * N + n0 + c4);
    *reinterpret_cast<f32x4*>(&tile[r][c4]) = v;
    __syncthreads();
    int nr = t >> 3, kc = (t & 7) * 4;
    bf16 o4[4];
    o4[0] = __float2bfloat16(tile[kc + 0][nr]);
    o4[1] = __float2bfloat16(tile[kc + 1][nr]);
    o4[2] = __float2bfloat16(tile[kc + 2][nr]);
    o4[3] = __float2bfloat16(tile[kc + 3][nr]);
    *reinterpret_cast<u64*>(Wt + (size_t)(n0 + nr) * K + k0 + kc) = *reinterpret_cast<const u64*>(o4);
}

// 3-matrix variant for fused QKV weight transpose (z selects matrix)
__global__ __launch_bounds__(256) void transpose_cvt3_kernel(
    const float* __restrict__ Wa, const float* __restrict__ Wb, const float* __restrict__ Wc,
    bf16* __restrict__ Wt, int K, int N)
{
    __shared__ float tile[32][36];
    const float* W = blockIdx.z == 0 ? Wa : (blockIdx.z == 1 ? Wb : Wc);
    bf16* dst = Wt + (size_t)blockIdx.z * N * K;
    int n0 = blockIdx.x * 32, k0 = blockIdx.y * 32;
    int t = threadIdx.x;
    int r = t >> 3, c4 = (t & 7) * 4;
    f32x4 v = *reinterpret_cast<const f32x4*>(W + (size_t)(k0 + r) * N + n0 + c4);
    *reinterpret_cast<f32x4*>(&tile[r][c4]) = v;
    __syncthreads();
    int nr = t >> 3, kc = (t & 7) * 4;
    bf16 o4[4];
    o4[0] = __float2bfloat16(tile[kc + 0][nr]);
    o4[1] = __float2bfloat16(tile[kc + 1][nr]);
    o4[2] = __float2bfloat16(tile[kc + 2][nr]);
    o4[3] = __float2bfloat16(tile[kc + 3][nr]);
    *reinterpret_cast<u64*>(dst + (size_t)(n0 + nr) * K + k0 + kc) = *reinterpret_cast<const u64*>(o4);
}

// ---------------- fused: hb = bf16(xnf); out = xnf + b2 ----------------
__global__ __launch_bounds__(256) void cvt_prefill_kernel(
    const float* __restrict__ xnf, const float* __restrict__ bias,
    bf16* __restrict__ hb, float* __restrict__ o, int N)
{
    int i = (blockIdx.x * 256 + threadIdx.x) * 8;
    int col = i % N;
    f32x4 a = *reinterpret_cast<const f32x4*>(xnf + i);
    f32x4 b = *reinterpret_cast<const f32x4*>(xnf + i + 4);
    bf16 r[8];
#pragma unroll
    for (int j = 0; j < 4; j++) { r[j] = __float2bfloat16(a[j]); r[4 + j] = __float2bfloat16(b[j]); }
    *reinterpret_cast<u32x4*>(hb + i) = *reinterpret_cast<const u32x4*>(r);
    f32x4 b0 = *reinterpret_cast<const f32x4*>(bias + col);
    f32x4 b1v = *reinterpret_cast<const f32x4*>(bias + col + 4);
    f32x4 o0 = {a[0] + b0[0], a[1] + b0[1], a[2] + b0[2], a[3] + b0[3]};
    f32x4 o1 = {b[0] + b1v[0], b[1] + b1v[1], b[2] + b1v[2], b[3] + b1v[3]};
    *reinterpret_cast<f32x4*>(o + i) = o0;
    *reinterpret_cast<f32x4*>(o + i + 4) = o1;
}

// ---------------- 128x128 bf16 MFMA GEMM (m97 structure, BK=64, swizzled) ------
// EPI 0: Cb = bf16(acc);  EPI 2: Cb = bf16(gelu(acc+bias));  EPI 4: atomicAdd(Cf, acc)
template <int EPI>
__global__ __launch_bounds__(256, 4) void gemm_kernel(
    const bf16* __restrict__ A, const bf16* __restrict__ Bt,
    int M, int N, int K, int Ksplit,
    bf16* Cb, float* Cf, const float* __restrict__ bias)
{
    __shared__ __align__(16) bf16 As[128 * 64];
    __shared__ __align__(16) bf16 Bs[128 * 64];
    int m0 = blockIdx.y * 128, n0 = blockIdx.x * 128;
    int kbeg = blockIdx.z * Ksplit, kend = kbeg + Ksplit;
    int tid = threadIdx.x;
    int lane = tid & 63, w = tid >> 6;
    int wr = w >> 1, wc = w & 1;
    int l15 = lane & 15, lhi = lane >> 4;

    int srow = lane >> 3;
    int scol = ((lane & 7) ^ (lane >> 3)) * 8;

    const f32x4 zero4 = {0.f, 0.f, 0.f, 0.f};
    f32x4 acc[4][4];
#pragma unroll
    for (int m = 0; m < 4; m++)
#pragma unroll
        for (int n = 0; n < 4; n++) acc[m][n] = zero4;

    for (int k0 = kbeg; k0 < kend; k0 += 64) {
        __syncthreads();
#pragma unroll
        for (int c = 0; c < 4; c++) {
            int row = w * 32 + c * 8 + srow;
            gload_lds16(A + (size_t)(m0 + row) * K + k0 + scol,
                        (char*)As + w * 4096 + c * 1024);
            gload_lds16(Bt + (size_t)(n0 + row) * K + k0 + scol,
                        (char*)Bs + w * 4096 + c * 1024);
        }
        __syncthreads();
#pragma unroll
        for (int ks = 0; ks < 2; ks++) {
            bf16x8 af[4], bfr[4];
#pragma unroll
            for (int m = 0; m < 4; m++) {
                int r = wr * 64 + m * 16 + l15;
                af[m] = *reinterpret_cast<const bf16x8*>(
                    &As[r * 64 + (((ks << 2) + lhi) ^ (r & 7)) * 8]);
            }
#pragma unroll
            for (int n = 0; n < 4; n++) {
                int r = wc * 64 + n * 16 + l15;
                bfr[n] = *reinterpret_cast<const bf16x8*>(
                    &Bs[r * 64 + (((ks << 2) + lhi) ^ (r & 7)) * 8]);
            }
#pragma unroll
            for (int m = 0; m < 4; m++)
#pragma unroll
                for (int n = 0; n < 4; n++)
                    acc[m][n] = __builtin_amdgcn_mfma_f32_16x16x32_bf16(af[m], bfr[n], acc[m][n], 0, 0, 0);
        }
    }

#pragma unroll
    for (int m = 0; m < 4; m++) {
        int row = m0 + wr * 64 + m * 16 + lhi * 4;
#pragma unroll
        for (int n = 0; n < 4; n++) {
            int col = n0 + wc * 64 + n * 16 + l15;
#pragma unroll
            for (int j = 0; j < 4; j++) {
                float vv = acc[m][n][j];
                size_t idx = (size_t)(row + j) * N + col;
                if (EPI == 0) {
                    Cb[idx] = __float2bfloat16(vv);
                } else if (EPI == 2) {
                    float o = vv + bias[col];
                    float u = 1.5957691216057308f * (o + 0.044715f * o * o * o);
                    Cb[idx] = __float2bfloat16(o / (1.0f + __expf(-u)));
                } else {
                    atomicAdd(&Cf[idx], vv);
                }
            }
        }
    }
}

// ---------------- flash-style causal attention, 8-wave QBLK=128 ----------------
// Grid NH*(Sq/128) work-descending, 512 threads; wave w owns q rows qb*128+w*16.
// LDS 70.7KB -> 2 blocks/CU = 16 waves/CU. K double-buffered via gload_lds
// (issued a full tile early); V single-buffered: regs loaded early, ds_write
// between barrier1 (PV reads done) and barrier2 (publish + K-DMA drain).
// Per-wave causal skip keeps barriers uniform. setprio around MFMA clusters.
__global__ __launch_bounds__(512) void attn_kernel(
    const bf16* __restrict__ qkv, bf16* __restrict__ o)
{
    __shared__ __align__(16) bf16 KsF[2][64 * 128];   // swizzled: slot s of row r = block s^(r&7)
    __shared__ __align__(16) bf16 VtF[128 * 72];      // V^T, kv-block XOR swizzle (single buffer)
    __shared__ __align__(16) bf16 Pl[8][16][76];      // per-wave P tile, padded stride
    int rank = blockIdx.x;
    int qb = (Sq / 128 - 1) - rank / NH;   // heaviest first
    int head = rank % NH;
    const bf16* q = qkv + head * DH;
    const bf16* k = qkv + HDim + head * DH;
    const bf16* v = qkv + 2 * HDim + head * DH;
    int tid = threadIdx.x, lane = tid & 63, w = tid >> 6;   // w 0..7
    int l15 = lane & 15, lhi = lane >> 4;
    int qrow0 = qb * 128 + w * 16;

    bf16x8 aq[4];
    const bf16* qbase = q + (size_t)(qrow0 + l15) * QKVDim;
#pragma unroll
    for (int kk = 0; kk < 4; kk++)
        aq[kk] = *reinterpret_cast<const bf16x8*>(qbase + kk * 32 + lhi * 8);

    bf16x8 vones;
#pragma unroll
    for (int j = 0; j < 8; j++) vones[j] = (short)0x3F80;

    // staging maps (bijective; bank-audited)
    int vkv = lhi * 2 + (w & 1) + (w >> 1) * 8;   // 0..31; +i*32
    int vd0 = l15 * 8;
    int vxr = l15 & 7;
    const bf16* vbase = v + (size_t)vkv * QKVDim + vd0;

    const f32x4 zero4 = {0.f, 0.f, 0.f, 0.f};
    f32x4 acc_o[8];
#pragma unroll
    for (int db = 0; db < 8; db++) acc_o[db] = zero4;
    f32x4 acc_l = zero4;
    float mrow[4];
#pragma unroll
    for (int r = 0; r < 4; r++) mrow[r] = -1e30f;

    int nt = 2 * qb + 2;

    // prologue: K(0) -> KsF[0] via DMA; V(0) -> VtF directly
    {
#pragma unroll
        for (int c = 0; c < 2; c++) {
            int row = w * 8 + c * 4 + lhi;
            int cb = l15 ^ (row & 7);
            gload_lds16(k + (size_t)row * QKVDim + cb * 8,
                        (char*)&KsF[0][0] + w * 2048 + c * 1024);
        }
#pragma unroll
        for (int i = 0; i < 2; i++) {
            int kv = vkv + i * 32;
            bf16x8 vv = *reinterpret_cast<const bf16x8*>(vbase + (size_t)(i * 32) * QKVDim);
            int vb = kv >> 3, kr = kv & 7;
#pragma unroll
            for (int j = 0; j < 8; j++)
                VtF[(vd0 + j) * 72 + ((vb ^ vxr) << 3) + kr] = ((const bf16*)&vv)[j];
        }
        __syncthreads();   // drains vmcnt+lgkm: K(0), V(0) visible
    }

    for (int kb = 0; kb < nt; kb++) {
        int kv0 = kb * 64;
        int p = kb & 1;
        bf16x8 vreg[2];
        bool pref = (kb + 1 < nt);
        if (pref) {
            int nv0 = kv0 + 64;
#pragma unroll
            for (int c = 0; c < 2; c++) {
                int row = w * 8 + c * 4 + lhi;
                int cb = l15 ^ (row & 7);
                gload_lds16(k + (size_t)(nv0 + row) * QKVDim + cb * 8,
                            (char*)&KsF[p ^ 1][0] + w * 2048 + c * 1024);
            }
#pragma unroll
            for (int i = 0; i < 2; i++)
                vreg[i] = *reinterpret_cast<const bf16x8*>(
                    vbase + (size_t)(nv0 + i * 32) * QKVDim);
        }

        bool active = (kv0 <= qrow0 + 15);   // wave-uniform causal skip
        if (active) {
            // ---- QK^T on KsF[p] ----
            f32x4 sacc[4];
            __builtin_amdgcn_s_setprio(1);
#pragma unroll
            for (int nb = 0; nb < 4; nb++) {
                sacc[nb] = zero4;
                int krow = nb * 16 + l15;
#pragma unroll
                for (int kk = 0; kk < 4; kk++) {
                    const char* kp = (const char*)&KsF[p][0] + krow * 256 +
                                     ((kk * 64 + lhi * 16) ^ ((krow & 7) << 4));
                    bf16x8 bk = *reinterpret_cast<const bf16x8*>(kp);
                    sacc[nb] = __builtin_amdgcn_mfma_f32_16x16x32_bf16(aq[kk], bk, sacc[nb], 0, 0, 0);
                }
            }
            __builtin_amdgcn_s_setprio(0);

            bool msk = (kv0 + 63 > qrow0);
            float sv[4][4];
            float pm[4];
#pragma unroll
            for (int r = 0; r < 4; r++) pm[r] = -1e30f;
#pragma unroll
            for (int nb = 0; nb < 4; nb++) {
                int kvc = kv0 + nb * 16 + l15;
#pragma unroll
                for (int r = 0; r < 4; r++) {
                    int qr = qrow0 + lhi * 4 + r;
                    float s = sacc[nb][r] * ATT_SCALE;
                    if (msk && kvc > qr) s = -1e30f;
                    sv[nb][r] = s;
                    pm[r] = fmaxf(pm[r], s);
                }
            }
#pragma unroll
            for (int off = 1; off < 16; off <<= 1)
#pragma unroll
                for (int r = 0; r < 4; r++)
                    pm[r] = fmaxf(pm[r], __shfl_xor(pm[r], off));

            // defer-max (THR=8)
            float nm[4];
            bool need = false;
#pragma unroll
            for (int r = 0; r < 4; r++) {
                nm[r] = fmaxf(mrow[r], pm[r]);
                need = need || (pm[r] > mrow[r] + 8.f);
            }
            if (__any(need)) {
#pragma unroll
                for (int r = 0; r < 4; r++) {
                    float sc = __expf(mrow[r] - nm[r]);
                    mrow[r] = nm[r];
                    acc_l[r] *= sc;
#pragma unroll
                    for (int db = 0; db < 8; db++) acc_o[db][r] *= sc;
                }
            }

#pragma unroll
            for (int nb = 0; nb < 4; nb++)
#pragma unroll
                for (int r = 0; r < 4; r++)
                    sv[nb][r] = __expf(sv[nb][r] - mrow[r]);

            // P -> LDS (per-wave tile)
#pragma unroll
            for (int nb = 0; nb < 4; nb++)
#pragma unroll
                for (int r = 0; r < 4; r++)
                    Pl[w][lhi * 4 + r][nb * 16 + l15] = __float2bfloat16(sv[nb][r]);

            // O += P V ; l += P * ones
            __builtin_amdgcn_s_setprio(1);
#pragma unroll
            for (int ks = 0; ks < 2; ks++) {
                bf16x8 ap = *reinterpret_cast<const bf16x8*>(&Pl[w][l15][ks * 32 + lhi * 8]);
                acc_l = __builtin_amdgcn_mfma_f32_16x16x32_bf16(ap, vones, acc_l, 0, 0, 0);
#pragma unroll
                for (int db = 0; db < 8; db++) {
                    int dv = db * 16 + l15;
                    int blk = (ks * 4 + lhi) ^ ((dv >> 3) & 7);
                    bf16x8 bv = *reinterpret_cast<const bf16x8*>(&VtF[dv * 72 + blk * 8]);
                    acc_o[db] = __builtin_amdgcn_mfma_f32_16x16x32_bf16(ap, bv, acc_o[db], 0, 0, 0);
                }
            }
            __builtin_amdgcn_s_setprio(0);
        }

        __syncthreads();   // barrier1: all waves done reading VtF
        if (pref) {
#pragma unroll
            for (int i = 0; i < 2; i++) {
                int kv = vkv + i * 32;
                int vb = kv >> 3, kr = kv & 7;
#pragma unroll
                for (int j = 0; j < 8; j++)
                    VtF[(vd0 + j) * 72 + ((vb ^ vxr) << 3) + kr] = ((const bf16*)&vreg[i])[j];
            }
        }
        __syncthreads();   // barrier2: V(kb+1) published; K(kb+1) DMA drained
    }

#pragma unroll
    for (int db = 0; db < 8; db++)
#pragma unroll
        for (int r = 0; r < 4; r++) {
            int qr = qrow0 + lhi * 4 + r;
            float val = acc_o[db][r] / acc_l[r];
            o[(size_t)qr * HDim + head * DH + db * 16 + l15] = __float2bfloat16(val);
        }
}

// ---------------- host launch ----------------
extern "C" void kernel_launch(void* const* d_in, const int* in_sizes, int n_in,
                              void* d_out, int out_size, void* d_ws, size_t ws_size,
                              hipStream_t stream)
{
    const float* x     = (const float*)d_in[0];
    const float* ln_g  = (const float*)d_in[1];
    const float* ln_b  = (const float*)d_in[2];
    const float* attng = (const float*)d_in[3];
    const float* Wq    = (const float*)d_in[4];
    const float* Wk    = (const float*)d_in[5];
    const float* Wv    = (const float*)d_in[6];
    const float* Wo    = (const float*)d_in[7];
    const float* W1    = (const float*)d_in[8];
    const float* b1    = (const float*)d_in[9];
    const float* W2    = (const float*)d_in[10];
    const float* b2    = (const float*)d_in[11];
    float* out = (float*)d_out;
    char* ws = (char*)d_ws;

    bf16*  wbuf = (bf16*)(ws + 0);           // 38 MB: transposed weights
    float* xnf  = (float*)(ws + 39845888);   // 16 MB: LN out fp32 -> x2 after Wo accum
    bf16*  hbuf = (bf16*)(ws + 56623104);    //  8 MB: rmsnorm bf16 -> x2 bf16
    bf16*  qkv  = (bf16*)(ws + 65011712);    // 36 MB: fused q|k|v; later FFN hidden
    bf16*  ob_  = (bf16*)(ws + 102760448);   // 12 MB: attention out
    bf16*  gb_  = qkv;

    ln_rms_kernel<<<Sq, 256, 0, stream>>>(x, ln_g, ln_b, attng, xnf, hbuf);

    transpose_cvt3_kernel<<<dim3(HDim / 32, Dm / 32, 3), 256, 0, stream>>>(
        Wq, Wk, Wv, wbuf, Dm, HDim);
    gemm_kernel<0><<<dim3(QKVDim / 128, Sq / 128, 1), 256, 0, stream>>>(
        hbuf, wbuf, Sq, QKVDim, Dm, Dm, qkv, nullptr, nullptr);

    attn_kernel<<<dim3(NH * Sq / 128), 512, 0, stream>>>(qkv, ob_);

    transpose_cvt_kernel<<<dim3(Dm / 32, HDim / 32), 256, 0, stream>>>(Wo, wbuf, HDim, Dm);
    gemm_kernel<4><<<dim3(Dm / 128, Sq / 128, 2), 256, 0, stream>>>(
        ob_, wbuf, Sq, Dm, HDim, HDim / 2, nullptr, xnf, nullptr);
    cvt_prefill_kernel<<<(Sq * Dm) / (256 * 8), 256, 0, stream>>>(xnf, b2, hbuf, out, Dm);

    transpose_cvt_kernel<<<dim3(FF / 32, Dm / 32), 256, 0, stream>>>(W1, wbuf, Dm, FF);
    gemm_kernel<2><<<dim3(FF / 128, Sq / 128, 1), 256, 0, stream>>>(
        hbuf, wbuf, Sq, FF, Dm, Dm, gb_, nullptr, b1);

    transpose_cvt_kernel<<<dim3(Dm / 32, FF / 32), 256, 0, stream>>>(W2, wbuf, FF, Dm);
    gemm_kernel<4><<<dim3(Dm / 128, Sq / 128, 2), 256, 0, stream>>>(
        gb_, wbuf, Sq, Dm, FF, FF / 2, nullptr, out, nullptr);
}

// Round 15
// 449.278 us; speedup vs baseline: 1.1464x; 1.0125x over previous
//
#include <hip/hip_runtime.h>
#include <hip/hip_bf16.h>

#define Sq 2048
#define Dm 2048
#define HDim 3072
#define QKVDim 9216
#define NH 24
#define DH 128
#define FF 8192
#define ATT_SCALE 0.08838834764831845f

using bf16 = __hip_bfloat16;
typedef __attribute__((ext_vector_type(8))) short bf16x8;
typedef __attribute__((ext_vector_type(4))) float f32x4;
typedef unsigned int u32;
typedef unsigned long long u64;
typedef __attribute__((ext_vector_type(4))) u32 u32x4;

__device__ __forceinline__ void gload_lds16(const void* g, void* l) {
    __builtin_amdgcn_global_load_lds(
        (const __attribute__((address_space(1))) void*)g,
        (__attribute__((address_space(3))) void*)l, 16, 0, 0);
}

// ---------------- LayerNorm + RMSNorm fused ----------------
__global__ __launch_bounds__(256) void ln_rms_kernel(
    const float* __restrict__ x, const float* __restrict__ g, const float* __restrict__ b,
    const float* __restrict__ ag, float* __restrict__ xnf, bf16* __restrict__ h)
{
    __shared__ float redA[4], redB[4], redC[4];
    int row = blockIdx.x;
    int t = threadIdx.x;
    int lane = t & 63, wid = t >> 6;
    const float* xr = x + (size_t)row * Dm;

    float v[8];
    float sum = 0.f, ssq = 0.f;
#pragma unroll
    for (int i = 0; i < 8; i++) {
        float f = xr[t + 256 * i];
        v[i] = f; sum += f; ssq += f * f;
    }
#pragma unroll
    for (int off = 32; off > 0; off >>= 1) {
        sum += __shfl_down(sum, off);
        ssq += __shfl_down(ssq, off);
    }
    if (lane == 0) { redA[wid] = sum; redB[wid] = ssq; }
    __syncthreads();
    sum = redA[0] + redA[1] + redA[2] + redA[3];
    ssq = redB[0] + redB[1] + redB[2] + redB[3];
    float mu = sum * (1.f / Dm);
    float var = ssq * (1.f / Dm) - mu * mu;
    float rstd = rsqrtf(var + 1e-5f);

    float xn[8];
    float s2 = 0.f;
#pragma unroll
    for (int i = 0; i < 8; i++) {
        int col = t + 256 * i;
        float xv = (v[i] - mu) * rstd * g[col] + b[col];
        xn[i] = xv;
        xnf[(size_t)row * Dm + col] = xv;
        s2 += xv * xv;
    }
#pragma unroll
    for (int off = 32; off > 0; off >>= 1) s2 += __shfl_down(s2, off);
    if (lane == 0) redC[wid] = s2;
    __syncthreads();
    s2 = redC[0] + redC[1] + redC[2] + redC[3];
    float rms = rsqrtf(s2 * (1.f / Dm) + 1e-5f);
#pragma unroll
    for (int i = 0; i < 8; i++) {
        int col = t + 256 * i;
        h[(size_t)row * Dm + col] = __float2bfloat16(xn[i] * rms * ag[col]);
    }
}

// ---------------- transpose + fp32->bf16 convert: W[K][N] -> Wt[N][K] ----------------
// 64x64 tile, 256 threads. float4 coalesced loads; LDS [64][65] f32 (writes
// conflict-free, transposed reads exact 2-way); bf16x8 16B coalesced stores.
__global__ __launch_bounds__(256) void transpose_cvt_kernel(
    const float* __restrict__ W, bf16* __restrict__ Wt, int K, int N)
{
    __shared__ float tile[64][65];
    int n0 = blockIdx.x * 64, k0 = blockIdx.y * 64;
    int t = threadIdx.x;
    int lr = t >> 4, lc = (t & 15) * 4;
#pragma unroll
    for (int i = 0; i < 4; i++) {
        int r = lr + i * 16;
        f32x4 v = *reinterpret_cast<const f32x4*>(W + (size_t)(k0 + r) * N + n0 + lc);
        *reinterpret_cast<f32x4*>(&tile[r][lc]) = v;
    }
    __syncthreads();
    int nr = t >> 3, kc = (t & 7) * 8;
#pragma unroll
    for (int i = 0; i < 2; i++) {
        int n = nr + i * 32;
        bf16 o8[8];
#pragma unroll
        for (int j = 0; j < 8; j++) o8[j] = __float2bfloat16(tile[kc + j][n]);
        *reinterpret_cast<u32x4*>(Wt + (size_t)(n0 + n) * K + k0 + kc) =
            *reinterpret_cast<const u32x4*>(o8);
    }
}

// 3-matrix variant for fused QKV weight transpose (z selects matrix)
__global__ __launch_bounds__(256) void transpose_cvt3_kernel(
    const float* __restrict__ Wa, const float* __restrict__ Wb, const float* __restrict__ Wc,
    bf16* __restrict__ Wt, int K, int N)
{
    __shared__ float tile[64][65];
    const float* W = blockIdx.z == 0 ? Wa : (blockIdx.z == 1 ? Wb : Wc);
    bf16* dst = Wt + (size_t)blockIdx.z * N * K;
    int n0 = blockIdx.x * 64, k0 = blockIdx.y * 64;
    int t = threadIdx.x;
    int lr = t >> 4, lc = (t & 15) * 4;
#pragma unroll
    for (int i = 0; i < 4; i++) {
        int r = lr + i * 16;
        f32x4 v = *reinterpret_cast<const f32x4*>(W + (size_t)(k0 + r) * N + n0 + lc);
        *reinterpret_cast<f32x4*>(&tile[r][lc]) = v;
    }
    __syncthreads();
    int nr = t >> 3, kc = (t & 7) * 8;
#pragma unroll
    for (int i = 0; i < 2; i++) {
        int n = nr + i * 32;
        bf16 o8[8];
#pragma unroll
        for (int j = 0; j < 8; j++) o8[j] = __float2bfloat16(tile[kc + j][n]);
        *reinterpret_cast<u32x4*>(dst + (size_t)(n0 + n) * K + k0 + kc) =
            *reinterpret_cast<const u32x4*>(o8);
    }
}

// ---------------- fused: hb = bf16(xnf); out = xnf + b2 ----------------
__global__ __launch_bounds__(256) void cvt_prefill_kernel(
    const float* __restrict__ xnf, const float* __restrict__ bias,
    bf16* __restrict__ hb, float* __restrict__ o, int N)
{
    int i = (blockIdx.x * 256 + threadIdx.x) * 8;
    int col = i % N;
    f32x4 a = *reinterpret_cast<const f32x4*>(xnf + i);
    f32x4 b = *reinterpret_cast<const f32x4*>(xnf + i + 4);
    bf16 r[8];
#pragma unroll
    for (int j = 0; j < 4; j++) { r[j] = __float2bfloat16(a[j]); r[4 + j] = __float2bfloat16(b[j]); }
    *reinterpret_cast<u32x4*>(hb + i) = *reinterpret_cast<const u32x4*>(r);
    f32x4 b0 = *reinterpret_cast<const f32x4*>(bias + col);
    f32x4 b1v = *reinterpret_cast<const f32x4*>(bias + col + 4);
    f32x4 o0 = {a[0] + b0[0], a[1] + b0[1], a[2] + b0[2], a[3] + b0[3]};
    f32x4 o1 = {b[0] + b1v[0], b[1] + b1v[1], b[2] + b1v[2], b[3] + b1v[3]};
    *reinterpret_cast<f32x4*>(o + i) = o0;
    *reinterpret_cast<f32x4*>(o + i + 4) = o1;
}

// ---------------- 128x128 bf16 MFMA GEMM (m97 structure, BK=64, swizzled) ------
// EPI 0: Cb = bf16(acc);  EPI 2: Cb = bf16(gelu(acc+bias));  EPI 4: atomicAdd(Cf, acc)
template <int EPI>
__global__ __launch_bounds__(256, 4) void gemm_kernel(
    const bf16* __restrict__ A, const bf16* __restrict__ Bt,
    int M, int N, int K, int Ksplit,
    bf16* Cb, float* Cf, const float* __restrict__ bias)
{
    __shared__ __align__(16) bf16 As[128 * 64];
    __shared__ __align__(16) bf16 Bs[128 * 64];
    int m0 = blockIdx.y * 128, n0 = blockIdx.x * 128;
    int kbeg = blockIdx.z * Ksplit, kend = kbeg + Ksplit;
    int tid = threadIdx.x;
    int lane = tid & 63, w = tid >> 6;
    int wr = w >> 1, wc = w & 1;
    int l15 = lane & 15, lhi = lane >> 4;

    int srow = lane >> 3;
    int scol = ((lane & 7) ^ (lane >> 3)) * 8;

    const f32x4 zero4 = {0.f, 0.f, 0.f, 0.f};
    f32x4 acc[4][4];
#pragma unroll
    for (int m = 0; m < 4; m++)
#pragma unroll
        for (int n = 0; n < 4; n++) acc[m][n] = zero4;

    for (int k0 = kbeg; k0 < kend; k0 += 64) {
        __syncthreads();
#pragma unroll
        for (int c = 0; c < 4; c++) {
            int row = w * 32 + c * 8 + srow;
            gload_lds16(A + (size_t)(m0 + row) * K + k0 + scol,
                        (char*)As + w * 4096 + c * 1024);
            gload_lds16(Bt + (size_t)(n0 + row) * K + k0 + scol,
                        (char*)Bs + w * 4096 + c * 1024);
        }
        __syncthreads();
#pragma unroll
        for (int ks = 0; ks < 2; ks++) {
            bf16x8 af[4], bfr[4];
#pragma unroll
            for (int m = 0; m < 4; m++) {
                int r = wr * 64 + m * 16 + l15;
                af[m] = *reinterpret_cast<const bf16x8*>(
                    &As[r * 64 + (((ks << 2) + lhi) ^ (r & 7)) * 8]);
            }
#pragma unroll
            for (int n = 0; n < 4; n++) {
                int r = wc * 64 + n * 16 + l15;
                bfr[n] = *reinterpret_cast<const bf16x8*>(
                    &Bs[r * 64 + (((ks << 2) + lhi) ^ (r & 7)) * 8]);
            }
#pragma unroll
            for (int m = 0; m < 4; m++)
#pragma unroll
                for (int n = 0; n < 4; n++)
                    acc[m][n] = __builtin_amdgcn_mfma_f32_16x16x32_bf16(af[m], bfr[n], acc[m][n], 0, 0, 0);
        }
    }

#pragma unroll
    for (int m = 0; m < 4; m++) {
        int row = m0 + wr * 64 + m * 16 + lhi * 4;
#pragma unroll
        for (int n = 0; n < 4; n++) {
            int col = n0 + wc * 64 + n * 16 + l15;
#pragma unroll
            for (int j = 0; j < 4; j++) {
                float vv = acc[m][n][j];
                size_t idx = (size_t)(row + j) * N + col;
                if (EPI == 0) {
                    Cb[idx] = __float2bfloat16(vv);
                } else if (EPI == 2) {
                    float o = vv + bias[col];
                    float u = 1.5957691216057308f * (o + 0.044715f * o * o * o);
                    Cb[idx] = __float2bfloat16(o / (1.0f + __expf(-u)));
                } else {
                    atomicAdd(&Cf[idx], vv);
                }
            }
        }
    }
}

// ---------------- flash-style causal attention, 8-wave QBLK=128 ----------------
__global__ __launch_bounds__(512) void attn_kernel(
    const bf16* __restrict__ qkv, bf16* __restrict__ o)
{
    __shared__ __align__(16) bf16 KsF[2][64 * 128];   // swizzled: slot s of row r = block s^(r&7)
    __shared__ __align__(16) bf16 VtF[128 * 72];      // V^T, kv-block XOR swizzle (single buffer)
    __shared__ __align__(16) bf16 Pl[8][16][76];      // per-wave P tile, padded stride
    int rank = blockIdx.x;
    int qb = (Sq / 128 - 1) - rank / NH;   // heaviest first
    int head = rank % NH;
    const bf16* q = qkv + head * DH;
    const bf16* k = qkv + HDim + head * DH;
    const bf16* v = qkv + 2 * HDim + head * DH;
    int tid = threadIdx.x, lane = tid & 63, w = tid >> 6;   // w 0..7
    int l15 = lane & 15, lhi = lane >> 4;
    int qrow0 = qb * 128 + w * 16;

    bf16x8 aq[4];
    const bf16* qbase = q + (size_t)(qrow0 + l15) * QKVDim;
#pragma unroll
    for (int kk = 0; kk < 4; kk++)
        aq[kk] = *reinterpret_cast<const bf16x8*>(qbase + kk * 32 + lhi * 8);

    bf16x8 vones;
#pragma unroll
    for (int j = 0; j < 8; j++) vones[j] = (short)0x3F80;

    int vkv = lhi * 2 + (w & 1) + (w >> 1) * 8;   // 0..31; +i*32
    int vd0 = l15 * 8;
    int vxr = l15 & 7;
    const bf16* vbase = v + (size_t)vkv * QKVDim + vd0;

    const f32x4 zero4 = {0.f, 0.f, 0.f, 0.f};
    f32x4 acc_o[8];
#pragma unroll
    for (int db = 0; db < 8; db++) acc_o[db] = zero4;
    f32x4 acc_l = zero4;
    float mrow[4];
#pragma unroll
    for (int r = 0; r < 4; r++) mrow[r] = -1e30f;

    int nt = 2 * qb + 2;

    // prologue: K(0) -> KsF[0] via DMA; V(0) -> VtF directly
    {
#pragma unroll
        for (int c = 0; c < 2; c++) {
            int row = w * 8 + c * 4 + lhi;
            int cb = l15 ^ (row & 7);
            gload_lds16(k + (size_t)row * QKVDim + cb * 8,
                        (char*)&KsF[0][0] + w * 2048 + c * 1024);
        }
#pragma unroll
        for (int i = 0; i < 2; i++) {
            int kv = vkv + i * 32;
            bf16x8 vv = *reinterpret_cast<const bf16x8*>(vbase + (size_t)(i * 32) * QKVDim);
            int vb = kv >> 3, kr = kv & 7;
#pragma unroll
            for (int j = 0; j < 8; j++)
                VtF[(vd0 + j) * 72 + ((vb ^ vxr) << 3) + kr] = ((const bf16*)&vv)[j];
        }
        __syncthreads();
    }

    for (int kb = 0; kb < nt; kb++) {
        int kv0 = kb * 64;
        int p = kb & 1;
        bf16x8 vreg[2];
        bool pref = (kb + 1 < nt);
        if (pref) {
            int nv0 = kv0 + 64;
#pragma unroll
            for (int c = 0; c < 2; c++) {
                int row = w * 8 + c * 4 + lhi;
                int cb = l15 ^ (row & 7);
                gload_lds16(k + (size_t)(nv0 + row) * QKVDim + cb * 8,
                            (char*)&KsF[p ^ 1][0] + w * 2048 + c * 1024);
            }
#pragma unroll
            for (int i = 0; i < 2; i++)
                vreg[i] = *reinterpret_cast<const bf16x8*>(
                    vbase + (size_t)(nv0 + i * 32) * QKVDim);
        }

        bool active = (kv0 <= qrow0 + 15);   // wave-uniform causal skip
        if (active) {
            f32x4 sacc[4];
            __builtin_amdgcn_s_setprio(1);
#pragma unroll
            for (int nb = 0; nb < 4; nb++) {
                sacc[nb] = zero4;
                int krow = nb * 16 + l15;
#pragma unroll
                for (int kk = 0; kk < 4; kk++) {
                    const char* kp = (const char*)&KsF[p][0] + krow * 256 +
                                     ((kk * 64 + lhi * 16) ^ ((krow & 7) << 4));
                    bf16x8 bk = *reinterpret_cast<const bf16x8*>(kp);
                    sacc[nb] = __builtin_amdgcn_mfma_f32_16x16x32_bf16(aq[kk], bk, sacc[nb], 0, 0, 0);
                }
            }
            __builtin_amdgcn_s_setprio(0);

            bool msk = (kv0 + 63 > qrow0);
            float sv[4][4];
            float pm[4];
#pragma unroll
            for (int r = 0; r < 4; r++) pm[r] = -1e30f;
#pragma unroll
            for (int nb = 0; nb < 4; nb++) {
                int kvc = kv0 + nb * 16 + l15;
#pragma unroll
                for (int r = 0; r < 4; r++) {
                    int qr = qrow0 + lhi * 4 + r;
                    float s = sacc[nb][r] * ATT_SCALE;
                    if (msk && kvc > qr) s = -1e30f;
                    sv[nb][r] = s;
                    pm[r] = fmaxf(pm[r], s);
                }
            }
#pragma unroll
            for (int off = 1; off < 16; off <<= 1)
#pragma unroll
                for (int r = 0; r < 4; r++)
                    pm[r] = fmaxf(pm[r], __shfl_xor(pm[r], off));

            float nm[4];
            bool need = false;
#pragma unroll
            for (int r = 0; r < 4; r++) {
                nm[r] = fmaxf(mrow[r], pm[r]);
                need = need || (pm[r] > mrow[r] + 8.f);
            }
            if (__any(need)) {
#pragma unroll
                for (int r = 0; r < 4; r++) {
                    float sc = __expf(mrow[r] - nm[r]);
                    mrow[r] = nm[r];
                    acc_l[r] *= sc;
#pragma unroll
                    for (int db = 0; db < 8; db++) acc_o[db][r] *= sc;
                }
            }

#pragma unroll
            for (int nb = 0; nb < 4; nb++)
#pragma unroll
                for (int r = 0; r < 4; r++)
                    sv[nb][r] = __expf(sv[nb][r] - mrow[r]);

#pragma unroll
            for (int nb = 0; nb < 4; nb++)
#pragma unroll
                for (int r = 0; r < 4; r++)
                    Pl[w][lhi * 4 + r][nb * 16 + l15] = __float2bfloat16(sv[nb][r]);

            __builtin_amdgcn_s_setprio(1);
#pragma unroll
            for (int ks = 0; ks < 2; ks++) {
                bf16x8 ap = *reinterpret_cast<const bf16x8*>(&Pl[w][l15][ks * 32 + lhi * 8]);
                acc_l = __builtin_amdgcn_mfma_f32_16x16x32_bf16(ap, vones, acc_l, 0, 0, 0);
#pragma unroll
                for (int db = 0; db < 8; db++) {
                    int dv = db * 16 + l15;
                    int blk = (ks * 4 + lhi) ^ ((dv >> 3) & 7);
                    bf16x8 bv = *reinterpret_cast<const bf16x8*>(&VtF[dv * 72 + blk * 8]);
                    acc_o[db] = __builtin_amdgcn_mfma_f32_16x16x32_bf16(ap, bv, acc_o[db], 0, 0, 0);
                }
            }
            __builtin_amdgcn_s_setprio(0);
        }

        __syncthreads();   // barrier1: all waves done reading VtF
        if (pref) {
#pragma unroll
            for (int i = 0; i < 2; i++) {
                int kv = vkv + i * 32;
                int vb = kv >> 3, kr = kv & 7;
#pragma unroll
                for (int j = 0; j < 8; j++)
                    VtF[(vd0 + j) * 72 + ((vb ^ vxr) << 3) + kr] = ((const bf16*)&vreg[i])[j];
            }
        }
        __syncthreads();   // barrier2: V(kb+1) published; K(kb+1) DMA drained
    }

#pragma unroll
    for (int db = 0; db < 8; db++)
#pragma unroll
        for (int r = 0; r < 4; r++) {
            int qr = qrow0 + lhi * 4 + r;
            float val = acc_o[db][r] / acc_l[r];
            o[(size_t)qr * HDim + head * DH + db * 16 + l15] = __float2bfloat16(val);
        }
}

// ---------------- host launch ----------------
extern "C" void kernel_launch(void* const* d_in, const int* in_sizes, int n_in,
                              void* d_out, int out_size, void* d_ws, size_t ws_size,
                              hipStream_t stream)
{
    const float* x     = (const float*)d_in[0];
    const float* ln_g  = (const float*)d_in[1];
    const float* ln_b  = (const float*)d_in[2];
    const float* attng = (const float*)d_in[3];
    const float* Wq    = (const float*)d_in[4];
    const float* Wk    = (const float*)d_in[5];
    const float* Wv    = (const float*)d_in[6];
    const float* Wo    = (const float*)d_in[7];
    const float* W1    = (const float*)d_in[8];
    const float* b1    = (const float*)d_in[9];
    const float* W2    = (const float*)d_in[10];
    const float* b2    = (const float*)d_in[11];
    float* out = (float*)d_out;
    char* ws = (char*)d_ws;

    bf16*  wbuf = (bf16*)(ws + 0);           // 38 MB: transposed weights
    float* xnf  = (float*)(ws + 39845888);   // 16 MB: LN out fp32 -> x2 after Wo accum
    bf16*  hbuf = (bf16*)(ws + 56623104);    //  8 MB: rmsnorm bf16 -> x2 bf16
    bf16*  qkv  = (bf16*)(ws + 65011712);    // 36 MB: fused q|k|v; later FFN hidden
    bf16*  ob_  = (bf16*)(ws + 102760448);   // 12 MB: attention out
    bf16*  gb_  = qkv;

    ln_rms_kernel<<<Sq, 256, 0, stream>>>(x, ln_g, ln_b, attng, xnf, hbuf);

    transpose_cvt3_kernel<<<dim3(HDim / 64, Dm / 64, 3), 256, 0, stream>>>(
        Wq, Wk, Wv, wbuf, Dm, HDim);
    gemm_kernel<0><<<dim3(QKVDim / 128, Sq / 128, 1), 256, 0, stream>>>(
        hbuf, wbuf, Sq, QKVDim, Dm, Dm, qkv, nullptr, nullptr);

    attn_kernel<<<dim3(NH * Sq / 128), 512, 0, stream>>>(qkv, ob_);

    transpose_cvt_kernel<<<dim3(Dm / 64, HDim / 64), 256, 0, stream>>>(Wo, wbuf, HDim, Dm);
    gemm_kernel<4><<<dim3(Dm / 128, Sq / 128, 2), 256, 0, stream>>>(
        ob_, wbuf, Sq, Dm, HDim, HDim / 2, nullptr, xnf, nullptr);
    cvt_prefill_kernel<<<(Sq * Dm) / (256 * 8), 256, 0, stream>>>(xnf, b2, hbuf, out, Dm);

    transpose_cvt_kernel<<<dim3(FF / 64, Dm / 64), 256, 0, stream>>>(W1, wbuf, Dm, FF);
    gemm_kernel<2><<<dim3(FF / 128, Sq / 128, 1), 256, 0, stream>>>(
        hbuf, wbuf, Sq, FF, Dm, Dm, gb_, nullptr, b1);

    transpose_cvt_kernel<<<dim3(Dm / 64, FF / 64), 256, 0, stream>>>(W2, wbuf, FF, Dm);
    gemm_kernel<4><<<dim3(Dm / 128, Sq / 128, 2), 256, 0, stream>>>(
        gb_, wbuf, Sq, Dm, FF, FF / 2, nullptr, out, nullptr);
}